// Round 10
// baseline (86.093 us; speedup 1.0000x reference)
//
#include <hip/hip_runtime.h>

typedef __attribute__((ext_vector_type(8))) short short8;
typedef __attribute__((ext_vector_type(4))) float f32x4;

#define D_KV   64
#define SEQ    4096
#define NBATCH 4
#define DMODEL 1024

static __device__ __forceinline__ unsigned short f32_to_bf16(float f) {
  unsigned u = __builtin_bit_cast(unsigned, f);
  u = (u + 0x7FFFu + ((u >> 16) & 1u)) >> 16;  // round-nearest-even
  return (unsigned short)u;
}

// async global->LDS DMA, 16B/lane; dst wave-uniform (HW adds lane*16)
static __device__ __forceinline__ void gload_lds16(const void* gsrc, void* ldst) {
  __builtin_amdgcn_global_load_lds(
      (const __attribute__((address_space(1))) void*)gsrc,
      (__attribute__((address_space(3))) void*)ldst, 16, 0, 0);
}

// ---------------- kernel 1: weights f32 -> bf16, MFMA-fragment order --------
// wfrag[((nt*32 + ks)*64 + lane)*8 + j] = W_mat[(nt&3)*16 + (lane&15)]
//                                             [ks*32 + (lane>>4)*8 + j]
__global__ __launch_bounds__(256) void wcvt_kernel(
    const float* __restrict__ wq, const float* __restrict__ wk,
    const float* __restrict__ wv, unsigned short* __restrict__ wfrag) {
  const int fid = blockIdx.x * 256 + threadIdx.x;  // 0..24575
  const int nt = fid >> 11, ks = (fid >> 6) & 31, lane = fid & 63;
  const int l16 = lane & 15, lq = lane >> 4;
  const float* w = (nt < 4) ? wq : (nt < 8) ? wk : wv;
  const float* src = w + ((nt & 3) * 16 + l16) * DMODEL + ks * 32 + lq * 8;
  short8 v;
#pragma unroll
  for (int j = 0; j < 8; ++j) v[j] = (short)f32_to_bf16(src[j]);
  *reinterpret_cast<short8*>(wfrag + (long)fid * 8) = v;
}

// ---------------- kernel 2: QKV projection, LDS-resident weights ------------
// 1024 blocks = 512 M-tiles(32 rows) x 2 nt-halves(6 nt). Weights staged to
// LDS in two 96KB K-phases via global_load_lds (linear both sides); x staged
// per-128-col chunk into a 3x8KB swizzled ring, loads issued 2 chunks ahead.
// Steady-state K-loop = ds_read + MFMA only (NO global loads).
__global__ __launch_bounds__(256, 1) void qkv_proj_kernel(
    const float* __restrict__ x, const unsigned short* __restrict__ wfrag,
    const float* __restrict__ bq, const float* __restrict__ bk,
    const float* __restrict__ bv,
    unsigned short* __restrict__ Qf, unsigned short* __restrict__ Kf,
    unsigned short* __restrict__ Vf) {
  __shared__ __align__(16) unsigned short wlds[49152];  // 96KB: 6nt x 16ks x 1KB
  __shared__ __align__(16) unsigned short xlds[12288];  // 24KB: 3 x (32r x 128c)
  const int tid = threadIdx.x, lane = tid & 63, wave = tid >> 6;
  const int l16 = lane & 15, lq = lane >> 4;
  const int h = blockIdx.x & 1;          // nt-half: nt = h*6 + ...
  const long rowbase = (long)(blockIdx.x >> 1) * 32;
  const int h6 = h * 6;
  const int sub = wave >> 1;             // row-subtile 0/1
  const int ntl0 = (wave & 1) * 3;       // local nt trio 0-2 / 3-5
  unsigned char* wl = (unsigned char*)wlds;
  unsigned char* xl = (unsigned char*)xlds;
  const unsigned char* wfb = (const unsigned char*)wfrag;

  // x staging map: thread -> row xr_ = tid>>3 (32 rows), 16 cols from (tid&7)*16
  const int xr_ = tid >> 3, xcb = (tid & 7) * 32;  // xcb = byte col offset (bf16)
  const float* xrow = x + (rowbase + xr_) * DMODEL;
  const int xswz = (xr_ & 7) << 4;

  f32x4 acc[3];
#pragma unroll
  for (int i = 0; i < 3; ++i) acc[i] = (f32x4){0.f, 0.f, 0.f, 0.f};

  f32x4 xg[4];  // in-flight x chunk (16 floats)

#define STAGE_W(ph)                                                           \
  {                                                                           \
    _Pragma("unroll")                                                         \
    for (int i2 = 0; i2 < 24; ++i2) {                                         \
      const int d = wave * 24576 + i2 * 1024;   /* byte in wlds */            \
      const int ntl = d >> 14, ksl = (d >> 10) & 15;                          \
      gload_lds16(wfb + (((h6 + ntl) * 32 + (ph) * 16 + ksl) << 10) + lane * 16, \
                  wl + d);                                                    \
    }                                                                         \
  }
#define XLOAD(c)                                                              \
  {                                                                           \
    const float* p = xrow + (c) * 128 + (tid & 7) * 16;                       \
    xg[0] = *reinterpret_cast<const f32x4*>(p);                               \
    xg[1] = *reinterpret_cast<const f32x4*>(p + 4);                           \
    xg[2] = *reinterpret_cast<const f32x4*>(p + 8);                           \
    xg[3] = *reinterpret_cast<const f32x4*>(p + 12);                          \
  }
#define XWRITE(c)                                                             \
  {                                                                           \
    short8 s0, s1;                                                            \
    _Pragma("unroll")                                                         \
    for (int j = 0; j < 4; ++j) {                                             \
      s0[j] = (short)f32_to_bf16(xg[0][j]);                                   \
      s0[4 + j] = (short)f32_to_bf16(xg[1][j]);                               \
      s1[j] = (short)f32_to_bf16(xg[2][j]);                                   \
      s1[4 + j] = (short)f32_to_bf16(xg[3][j]);                               \
    }                                                                         \
    unsigned char* base = xl + ((c) % 3) * 8192 + xr_ * 256;                  \
    *reinterpret_cast<short8*>(base + (xcb ^ xswz)) = s0;                     \
    *reinterpret_cast<short8*>(base + ((xcb + 16) ^ xswz)) = s1;              \
  }

  // prologue: weights phase 0 + x chunks 0,1
  STAGE_W(0);
  XLOAD(0); XWRITE(0);
  XLOAD(1); XWRITE(1);
  __syncthreads();  // drains weight DMA + x ds_writes

  const int arow = sub * 16 + l16;
  const int aswz = (arow & 7) << 4;

  for (int ck = 0; ck < 8; ++ck) {
    if (ck < 6) XLOAD(ck + 2);  // issue 2 chunks ahead
    const unsigned char* xbuf = xl + (ck % 3) * 8192 + arow * 256;
#pragma unroll
    for (int kc = 0; kc < 4; ++kc) {
      const short8 a = *reinterpret_cast<const short8*>(
          xbuf + ((kc * 64 + lq * 16) ^ aswz));
      const int ksl = (ck & 3) * 4 + kc;
#pragma unroll
      for (int i = 0; i < 3; ++i) {
        const short8 b = *reinterpret_cast<const short8*>(
            wl + (((ntl0 + i) * 16 + ksl) << 10) + lane * 16);
        acc[i] = __builtin_amdgcn_mfma_f32_16x16x32_bf16(a, b, acc[i], 0, 0, 0);
      }
    }
    __syncthreads();  // all waves done with buf ck%3 (and, at ck==3, ph0 weights)
    if (ck < 6) XWRITE(ck + 2);
    if (ck == 3) {
      STAGE_W(1);
      __syncthreads();  // drain weight DMA before ck=4 compute
    }
  }

#pragma unroll
  for (int i = 0; i < 3; ++i) {
    const int nt = h6 + ntl0 + i;
    const int mat = nt >> 2;
    const int dcol = ((nt & 3) << 4) | l16;
    const float bias = (mat == 0 ? bq : mat == 1 ? bk : bv)[dcol];
    const int c = dcol >> 5, lqp = (dcol >> 3) & 3, jj = dcol & 7;
#pragma unroll
    for (int rr = 0; rr < 4; ++rr) {
      const long t = rowbase + sub * 16 + lq * 4 + rr;
      const float sum = acc[i][rr] + bias;
      if (mat == 0) {
        Qf[(((t >> 4) * 2 + c) * 64 + lqp * 16 + (t & 15)) * 8 + jj] =
            f32_to_bf16(sum * 0.125f);  // fold 1/sqrt(64)
      } else if (mat == 1) {
        Kf[((((t >> 6) * 4 + ((t >> 4) & 3)) * 2 + c) * 64 + lqp * 16 +
            (t & 15)) * 8 + jj] = f32_to_bf16(sum);
      } else {
        Vf[((((t >> 6) * 4 + (dcol >> 4)) * 2 + ((t >> 5) & 1)) * 64 +
            ((t >> 3) & 3) * 16 + (dcol & 15)) * 8 + (t & 7)] =
            f32_to_bf16(sum);
      }
    }
  }
#undef STAGE_W
#undef XLOAD
#undef XWRITE
}

// ---------------- kernel 3: causal flash attention, swapped-operand ---------
// Unchanged from R4 (proven): 4 waves split KV round-robin, lane-local softmax
// via swapped MFMA operands, fragment-ordered Qf/Kf/Vf loads.
__global__ __launch_bounds__(256) void attn_kernel(
    const unsigned short* __restrict__ Qf, const unsigned short* __restrict__ Kf,
    const unsigned short* __restrict__ Vf, float* __restrict__ out) {
  __shared__ __align__(16) unsigned short p_lds[4][16][72];  // [wave][q][k]
  __shared__ __align__(16) float lds_o[4][16][68];           // [wave][q][d]
  __shared__ float lds_ml[4][16][2];
  __shared__ float lds_gl[16];

  const int tid = threadIdx.x;
  const int lane = tid & 63;
  const int wave = tid >> 6;
  const int l16 = lane & 15, lq = lane >> 4;
  const int b = blockIdx.y;
  const int tile = 255 - blockIdx.x;  // heavy tiles dispatch first
  const int qbase = tile * 16;
  const long qrow = (long)b * SEQ + qbase;

  short8 qf[2];
#pragma unroll
  for (int c = 0; c < 2; ++c)
    qf[c] = *reinterpret_cast<const short8*>(
        Qf + ((qrow >> 4) * 2 + c) * 512 + lane * 8);

  f32x4 o[4];  // O^T: o[dt][r] = O[q=l16][d=dt*16+lq*4+r]
#pragma unroll
  for (int dt = 0; dt < 4; ++dt) o[dt] = (f32x4){0.f, 0.f, 0.f, 0.f};
  float m = -INFINITY, ell = 0.f;  // per-lane state for q = qbase + l16

  const long ktile0 = (long)b * 64;
  const int nkv = qbase / 64 + 1;  // KV tiles of 64 cols
  for (int kt = wave; kt < nkv; kt += 4) {
    const int kvbase = kt * 64;
    const unsigned short* kb = Kf + (ktile0 + kt) * 4096 + lane * 8;
    const unsigned short* vb = Vf + (ktile0 + kt) * 4096 + lane * 8;
    f32x4 s[4];  // S^T: s[ct][r] = S[q=l16][k=kvbase+ct*16+lq*4+r]
#pragma unroll
    for (int ct = 0; ct < 4; ++ct) s[ct] = (f32x4){0.f, 0.f, 0.f, 0.f};
#pragma unroll
    for (int ct = 0; ct < 4; ++ct)
#pragma unroll
      for (int c = 0; c < 2; ++c) {
        short8 kf = *reinterpret_cast<const short8*>(kb + (ct * 2 + c) * 512);
        s[ct] = __builtin_amdgcn_mfma_f32_16x16x32_bf16(kf, qf[c], s[ct], 0, 0, 0);
      }
    if (kt == nkv - 1) {  // only the diagonal tile needs masking
      const int qg = qbase + l16;
#pragma unroll
      for (int ct = 0; ct < 4; ++ct)
#pragma unroll
        for (int r = 0; r < 4; ++r)
          if (kvbase + ct * 16 + lq * 4 + r > qg) s[ct][r] = -INFINITY;
    }
    // lane-local softmax over 16 held k values + 4-lane-group reduce
    float mx = -INFINITY;
#pragma unroll
    for (int ct = 0; ct < 4; ++ct)
#pragma unroll
      for (int r = 0; r < 4; ++r) mx = fmaxf(mx, s[ct][r]);
    mx = fmaxf(mx, __shfl_xor(mx, 16, 64));
    mx = fmaxf(mx, __shfl_xor(mx, 32, 64));
    const float nm = fmaxf(m, mx);
    const float alpha = __expf(m - nm);  // exp(-inf)=0 on first tile
    float rs = 0.f;
#pragma unroll
    for (int ct = 0; ct < 4; ++ct)
#pragma unroll
      for (int r = 0; r < 4; ++r) {
        const float p = __expf(s[ct][r] - nm);
        s[ct][r] = p;
        rs += p;
      }
    rs += __shfl_xor(rs, 16, 64);
    rs += __shfl_xor(rs, 32, 64);
    ell = ell * alpha + rs;
    m = nm;
#pragma unroll
    for (int dt = 0; dt < 4; ++dt) o[dt] *= alpha;
    // P^T (regs) -> p_lds[q][k] -> B-frag for PV. Per-wave buffer, no barrier.
#pragma unroll
    for (int ct = 0; ct < 4; ++ct)
#pragma unroll
      for (int r = 0; r < 4; ++r)
        p_lds[wave][l16][ct * 16 + lq * 4 + r] = f32_to_bf16(s[ct][r]);
    short8 pf[2];
#pragma unroll
    for (int c = 0; c < 2; ++c)
      pf[c] = *reinterpret_cast<const short8*>(&p_lds[wave][l16][c * 32 + lq * 8]);
#pragma unroll
    for (int dt = 0; dt < 4; ++dt)
#pragma unroll
      for (int c = 0; c < 2; ++c) {
        short8 vf = *reinterpret_cast<const short8*>(vb + (dt * 2 + c) * 512);
        o[dt] = __builtin_amdgcn_mfma_f32_16x16x32_bf16(vf, pf[c], o[dt], 0, 0, 0);
      }
  }

  // ---- cross-wave combine ----
  if (lane < 16) {
    lds_ml[wave][l16][0] = m;
    lds_ml[wave][l16][1] = ell;
  }
  __syncthreads();
  const float m0 = lds_ml[0][l16][0], m1 = lds_ml[1][l16][0];
  const float m2 = lds_ml[2][l16][0], m3 = lds_ml[3][l16][0];
  const float g = fmaxf(fmaxf(m0, m1), fmaxf(m2, m3));
  const float gl = lds_ml[0][l16][1] * __expf(m0 - g) +
                   lds_ml[1][l16][1] * __expf(m1 - g) +
                   lds_ml[2][l16][1] * __expf(m2 - g) +
                   lds_ml[3][l16][1] * __expf(m3 - g);
  const float myscale = __expf(m - g);
  if (wave == 0 && lane < 16) lds_gl[l16] = gl;
#pragma unroll
  for (int dt = 0; dt < 4; ++dt)
#pragma unroll
    for (int r = 0; r < 4; ++r)
      lds_o[wave][l16][dt * 16 + lq * 4 + r] = o[dt][r] * myscale;
  __syncthreads();
#pragma unroll
  for (int j = 0; j < 4; ++j) {
    const int e = tid + 256 * j;
    const int row = e >> 6, col = e & 63;
    const float sum = lds_o[0][row][col] + lds_o[1][row][col] +
                      lds_o[2][row][col] + lds_o[3][row][col];
    out[(qrow + row) * D_KV + col] = sum / lds_gl[row];
  }
}

// ---------------- launch ----------------------------------------------------
extern "C" void kernel_launch(void* const* d_in, const int* in_sizes, int n_in,
                              void* d_out, int out_size, void* d_ws, size_t ws_size,
                              hipStream_t stream) {
  const float* x  = (const float*)d_in[0];
  const float* wq = (const float*)d_in[1];
  const float* bq = (const float*)d_in[2];
  const float* wk = (const float*)d_in[3];
  const float* bk = (const float*)d_in[4];
  const float* wv = (const float*)d_in[5];
  const float* bv = (const float*)d_in[6];
  float* out = (float*)d_out;

  unsigned short* ws    = (unsigned short*)d_ws;
  unsigned short* wfrag = ws;              // 12*32*64*8 = 196608 shorts (384KB)
  unsigned short* Qf    = ws + 196608;     // 1024 tiles * 1024 = 1048576
  unsigned short* Kf    = Qf + 1048576;    // 256 kv-tiles * 4096
  unsigned short* Vf    = Kf + 1048576;

  wcvt_kernel<<<96, 256, 0, stream>>>(wq, wk, wv, wfrag);
  qkv_proj_kernel<<<1024, 256, 0, stream>>>(x, wfrag, bq, bk, bv, Qf, Kf, Vf);
  dim3 ag(256, NBATCH);
  attn_kernel<<<ag, 256, 0, stream>>>(Qf, Kf, Vf, out);
}

// Round 11
// 65.473 us; speedup vs baseline: 1.3150x; 1.3150x over previous
//
#include <hip/hip_runtime.h>

typedef __attribute__((ext_vector_type(8))) short short8;
typedef __attribute__((ext_vector_type(4))) float f32x4;

#define D_KV   64
#define SEQ    4096
#define NBATCH 4
#define DMODEL 1024

static __device__ __forceinline__ unsigned short f32_to_bf16(float f) {
  unsigned u = __builtin_bit_cast(unsigned, f);
  u = (u + 0x7FFFu + ((u >> 16) & 1u)) >> 16;  // round-nearest-even
  return (unsigned short)u;
}

// ---------------- kernel 1: weights f32 -> bf16, MFMA-fragment order --------
// wfrag[((nt*32 + ks)*64 + lane)*8 + j] = W_mat[(nt&3)*16 + (lane&15)]
//                                             [ks*32 + (lane>>4)*8 + j]
__global__ __launch_bounds__(256) void wcvt_kernel(
    const float* __restrict__ wq, const float* __restrict__ wk,
    const float* __restrict__ wv, unsigned short* __restrict__ wfrag) {
  const int fid = blockIdx.x * 256 + threadIdx.x;  // 0..24575
  const int nt = fid >> 11, ks = (fid >> 6) & 31, lane = fid & 63;
  const int l16 = lane & 15, lq = lane >> 4;
  const float* w = (nt < 4) ? wq : (nt < 8) ? wk : wv;
  const float* src = w + ((nt & 3) * 16 + l16) * DMODEL + ks * 32 + lq * 8;
  short8 v;
#pragma unroll
  for (int j = 0; j < 8; ++j) v[j] = (short)f32_to_bf16(src[j]);
  *reinterpret_cast<short8*>(wfrag + (long)fid * 8) = v;
}

// ---------------- kernel 2: QKV projection, high-MLP ------------------------
// 512 blocks x 32 rows. launch_bounds(256,1) frees the register allocator.
// x staged ONCE into 64KB XOR-swizzled LDS (1 barrier). K-loop fully unrolled
// with register-double-buffered weights: 12 independent 1KB loads issued
// before each chunk's MFMAs -> deep memory-level parallelism per wave.
__global__ __launch_bounds__(256, 1) void qkv_proj_kernel(
    const float* __restrict__ x, const unsigned short* __restrict__ wfrag,
    const float* __restrict__ bq, const float* __restrict__ bk,
    const float* __restrict__ bv,
    unsigned short* __restrict__ Qf, unsigned short* __restrict__ Kf,
    unsigned short* __restrict__ Vf) {
  __shared__ __align__(16) unsigned short lds_x[32 * 1024];  // 64KB swizzled
  const int tid = threadIdx.x, lane = tid & 63, wave = tid >> 6;
  const int l16 = lane & 15, lq = lane >> 4;
  const long rowbase = (long)blockIdx.x * 32;
  unsigned char* lx = (unsigned char*)lds_x;

  // ---- stage x tile (32 rows x 1024 f32), coalesced per 8-thread group ----
  {
    const int srow = tid >> 3, scol = (tid & 7) * 16;  // float units
    const float* xrow = x + (rowbase + srow) * DMODEL + scol;
    const int swz = (srow & 7) << 4;
    unsigned char* lbase = lx + srow * 2048;
#pragma unroll
    for (int s = 0; s < 8; ++s) {
      const f32x4 f0 = *reinterpret_cast<const f32x4*>(xrow + s * 128);
      const f32x4 f1 = *reinterpret_cast<const f32x4*>(xrow + s * 128 + 4);
      const f32x4 f2 = *reinterpret_cast<const f32x4*>(xrow + s * 128 + 8);
      const f32x4 f3 = *reinterpret_cast<const f32x4*>(xrow + s * 128 + 12);
      short8 s0, s1;
#pragma unroll
      for (int j = 0; j < 4; ++j) {
        s0[j]     = (short)f32_to_bf16(f0[j]);
        s0[4 + j] = (short)f32_to_bf16(f1[j]);
        s1[j]     = (short)f32_to_bf16(f2[j]);
        s1[4 + j] = (short)f32_to_bf16(f3[j]);
      }
      const int bcol = scol * 2 + s * 256;
      *reinterpret_cast<short8*>(lbase + (bcol ^ swz)) = s0;
      *reinterpret_cast<short8*>(lbase + ((bcol + 16) ^ swz)) = s1;
    }
  }
  __syncthreads();  // the only barrier

  // ---- K-loop: wave owns nt-trio `wave` for both 16-row subtiles ----------
  const unsigned short* wbase = wfrag + (long)(3 * wave) * 16384 + lane * 8;

  short8 bw[12];  // current chunk's weights: [i][kc] at j = i*4+kc
#pragma unroll
  for (int j = 0; j < 12; ++j)
    bw[j] = *reinterpret_cast<const short8*>(
        wbase + (long)(j >> 2) * 16384 + (j & 3) * 512);

  f32x4 acc[3][2];
#pragma unroll
  for (int i = 0; i < 3; ++i)
#pragma unroll
    for (int s = 0; s < 2; ++s) acc[i][s] = (f32x4){0.f, 0.f, 0.f, 0.f};

#pragma unroll
  for (int ck = 0; ck < 8; ++ck) {
    short8 bn[12];  // next chunk's weights, issued before this chunk's MFMAs
    if (ck < 7) {
#pragma unroll
      for (int j = 0; j < 12; ++j)
        bn[j] = *reinterpret_cast<const short8*>(
            wbase + (long)(j >> 2) * 16384 + ((ck + 1) * 4 + (j & 3)) * 512);
    }
    short8 a[4][2];
#pragma unroll
    for (int kc = 0; kc < 4; ++kc)
#pragma unroll
      for (int sub = 0; sub < 2; ++sub) {
        const int row = sub * 16 + l16;
        a[kc][sub] = *reinterpret_cast<const short8*>(
            lx + row * 2048 +
            (((ck * 4 + kc) * 64 + lq * 16) ^ ((row & 7) << 4)));
      }
#pragma unroll
    for (int kc = 0; kc < 4; ++kc)
#pragma unroll
      for (int i = 0; i < 3; ++i) {
        acc[i][0] = __builtin_amdgcn_mfma_f32_16x16x32_bf16(
            a[kc][0], bw[i * 4 + kc], acc[i][0], 0, 0, 0);
        acc[i][1] = __builtin_amdgcn_mfma_f32_16x16x32_bf16(
            a[kc][1], bw[i * 4 + kc], acc[i][1], 0, 0, 0);
      }
    if (ck < 7) {
#pragma unroll
      for (int j = 0; j < 12; ++j) bw[j] = bn[j];  // SSA rename (full unroll)
    }
  }

  // ---- epilogue: fragment-order stores (consumed directly by attn) --------
#pragma unroll
  for (int i = 0; i < 3; ++i) {
    const int nt = 3 * wave + i;
    const int mat = nt >> 2;
    const int dcol = ((nt & 3) << 4) | l16;
    const float bias = (mat == 0 ? bq : mat == 1 ? bk : bv)[dcol];
    const int c = dcol >> 5, lqp = (dcol >> 3) & 3, jj = dcol & 7;
#pragma unroll
    for (int sub = 0; sub < 2; ++sub)
#pragma unroll
      for (int rr = 0; rr < 4; ++rr) {
        const long t = rowbase + sub * 16 + lq * 4 + rr;
        const float sum = acc[i][sub][rr] + bias;
        if (mat == 0) {
          Qf[(((t >> 4) * 2 + c) * 64 + lqp * 16 + (t & 15)) * 8 + jj] =
              f32_to_bf16(sum * 0.125f);  // fold 1/sqrt(64)
        } else if (mat == 1) {
          Kf[((((t >> 6) * 4 + ((t >> 4) & 3)) * 2 + c) * 64 + lqp * 16 +
              (t & 15)) * 8 + jj] = f32_to_bf16(sum);
        } else {
          Vf[((((t >> 6) * 4 + (dcol >> 4)) * 2 + ((t >> 5) & 1)) * 64 +
              ((t >> 3) & 3) * 16 + (dcol & 15)) * 8 + (t & 7)] =
              f32_to_bf16(sum);
        }
      }
  }
}

// ---------------- kernel 3: causal flash attention, swapped-operand ---------
// Unchanged from R4 (proven): 4 waves split KV round-robin, lane-local softmax
// via swapped MFMA operands, fragment-ordered Qf/Kf/Vf loads.
__global__ __launch_bounds__(256) void attn_kernel(
    const unsigned short* __restrict__ Qf, const unsigned short* __restrict__ Kf,
    const unsigned short* __restrict__ Vf, float* __restrict__ out) {
  __shared__ __align__(16) unsigned short p_lds[4][16][72];  // [wave][q][k]
  __shared__ __align__(16) float lds_o[4][16][68];           // [wave][q][d]
  __shared__ float lds_ml[4][16][2];
  __shared__ float lds_gl[16];

  const int tid = threadIdx.x;
  const int lane = tid & 63;
  const int wave = tid >> 6;
  const int l16 = lane & 15, lq = lane >> 4;
  const int b = blockIdx.y;
  const int tile = 255 - blockIdx.x;  // heavy tiles dispatch first
  const int qbase = tile * 16;
  const long qrow = (long)b * SEQ + qbase;

  short8 qf[2];
#pragma unroll
  for (int c = 0; c < 2; ++c)
    qf[c] = *reinterpret_cast<const short8*>(
        Qf + ((qrow >> 4) * 2 + c) * 512 + lane * 8);

  f32x4 o[4];  // O^T: o[dt][r] = O[q=l16][d=dt*16+lq*4+r]
#pragma unroll
  for (int dt = 0; dt < 4; ++dt) o[dt] = (f32x4){0.f, 0.f, 0.f, 0.f};
  float m = -INFINITY, ell = 0.f;  // per-lane state for q = qbase + l16

  const long ktile0 = (long)b * 64;
  const int nkv = qbase / 64 + 1;  // KV tiles of 64 cols
  for (int kt = wave; kt < nkv; kt += 4) {
    const int kvbase = kt * 64;
    const unsigned short* kb = Kf + (ktile0 + kt) * 4096 + lane * 8;
    const unsigned short* vb = Vf + (ktile0 + kt) * 4096 + lane * 8;
    f32x4 s[4];  // S^T: s[ct][r] = S[q=l16][k=kvbase+ct*16+lq*4+r]
#pragma unroll
    for (int ct = 0; ct < 4; ++ct) s[ct] = (f32x4){0.f, 0.f, 0.f, 0.f};
#pragma unroll
    for (int ct = 0; ct < 4; ++ct)
#pragma unroll
      for (int c = 0; c < 2; ++c) {
        short8 kf = *reinterpret_cast<const short8*>(kb + (ct * 2 + c) * 512);
        s[ct] = __builtin_amdgcn_mfma_f32_16x16x32_bf16(kf, qf[c], s[ct], 0, 0, 0);
      }
    if (kt == nkv - 1) {  // only the diagonal tile needs masking
      const int qg = qbase + l16;
#pragma unroll
      for (int ct = 0; ct < 4; ++ct)
#pragma unroll
        for (int r = 0; r < 4; ++r)
          if (kvbase + ct * 16 + lq * 4 + r > qg) s[ct][r] = -INFINITY;
    }
    // lane-local softmax over 16 held k values + 4-lane-group reduce
    float mx = -INFINITY;
#pragma unroll
    for (int ct = 0; ct < 4; ++ct)
#pragma unroll
      for (int r = 0; r < 4; ++r) mx = fmaxf(mx, s[ct][r]);
    mx = fmaxf(mx, __shfl_xor(mx, 16, 64));
    mx = fmaxf(mx, __shfl_xor(mx, 32, 64));
    const float nm = fmaxf(m, mx);
    const float alpha = __expf(m - nm);  // exp(-inf)=0 on first tile
    float rs = 0.f;
#pragma unroll
    for (int ct = 0; ct < 4; ++ct)
#pragma unroll
      for (int r = 0; r < 4; ++r) {
        const float p = __expf(s[ct][r] - nm);
        s[ct][r] = p;
        rs += p;
      }
    rs += __shfl_xor(rs, 16, 64);
    rs += __shfl_xor(rs, 32, 64);
    ell = ell * alpha + rs;
    m = nm;
#pragma unroll
    for (int dt = 0; dt < 4; ++dt) o[dt] *= alpha;
    // P^T (regs) -> p_lds[q][k] -> B-frag for PV. Per-wave buffer, no barrier.
#pragma unroll
    for (int ct = 0; ct < 4; ++ct)
#pragma unroll
      for (int r = 0; r < 4; ++r)
        p_lds[wave][l16][ct * 16 + lq * 4 + r] = f32_to_bf16(s[ct][r]);
    short8 pf[2];
#pragma unroll
    for (int c = 0; c < 2; ++c)
      pf[c] = *reinterpret_cast<const short8*>(&p_lds[wave][l16][c * 32 + lq * 8]);
#pragma unroll
    for (int dt = 0; dt < 4; ++dt)
#pragma unroll
      for (int c = 0; c < 2; ++c) {
        short8 vf = *reinterpret_cast<const short8*>(vb + (dt * 2 + c) * 512);
        o[dt] = __builtin_amdgcn_mfma_f32_16x16x32_bf16(vf, pf[c], o[dt], 0, 0, 0);
      }
  }

  // ---- cross-wave combine ----
  if (lane < 16) {
    lds_ml[wave][l16][0] = m;
    lds_ml[wave][l16][1] = ell;
  }
  __syncthreads();
  const float m0 = lds_ml[0][l16][0], m1 = lds_ml[1][l16][0];
  const float m2 = lds_ml[2][l16][0], m3 = lds_ml[3][l16][0];
  const float g = fmaxf(fmaxf(m0, m1), fmaxf(m2, m3));
  const float gl = lds_ml[0][l16][1] * __expf(m0 - g) +
                   lds_ml[1][l16][1] * __expf(m1 - g) +
                   lds_ml[2][l16][1] * __expf(m2 - g) +
                   lds_ml[3][l16][1] * __expf(m3 - g);
  const float myscale = __expf(m - g);
  if (wave == 0 && lane < 16) lds_gl[l16] = gl;
#pragma unroll
  for (int dt = 0; dt < 4; ++dt)
#pragma unroll
    for (int r = 0; r < 4; ++r)
      lds_o[wave][l16][dt * 16 + lq * 4 + r] = o[dt][r] * myscale;
  __syncthreads();
#pragma unroll
  for (int j = 0; j < 4; ++j) {
    const int e = tid + 256 * j;
    const int row = e >> 6, col = e & 63;
    const float sum = lds_o[0][row][col] + lds_o[1][row][col] +
                      lds_o[2][row][col] + lds_o[3][row][col];
    out[(qrow + row) * D_KV + col] = sum / lds_gl[row];
  }
}

// ---------------- launch ----------------------------------------------------
extern "C" void kernel_launch(void* const* d_in, const int* in_sizes, int n_in,
                              void* d_out, int out_size, void* d_ws, size_t ws_size,
                              hipStream_t stream) {
  const float* x  = (const float*)d_in[0];
  const float* wq = (const float*)d_in[1];
  const float* bq = (const float*)d_in[2];
  const float* wk = (const float*)d_in[3];
  const float* bk = (const float*)d_in[4];
  const float* wv = (const float*)d_in[5];
  const float* bv = (const float*)d_in[6];
  float* out = (float*)d_out;

  unsigned short* ws    = (unsigned short*)d_ws;
  unsigned short* wfrag = ws;              // 12*32*64*8 = 196608 shorts (384KB)
  unsigned short* Qf    = ws + 196608;     // 1024 tiles * 1024 = 1048576
  unsigned short* Kf    = Qf + 1048576;    // 256 kv-tiles * 4096
  unsigned short* Vf    = Kf + 1048576;

  wcvt_kernel<<<96, 256, 0, stream>>>(wq, wk, wv, wfrag);
  qkv_proj_kernel<<<512, 256, 0, stream>>>(x, wfrag, bq, bk, bv, Qf, Kf, Vf);
  dim3 ag(256, NBATCH);
  attn_kernel<<<ag, 256, 0, stream>>>(Qf, Kf, Vf, out);
}

// Round 12
// 64.889 us; speedup vs baseline: 1.3268x; 1.0090x over previous
//
#include <hip/hip_runtime.h>

typedef __attribute__((ext_vector_type(8))) short short8;
typedef __attribute__((ext_vector_type(4))) float f32x4;

#define D_KV   64
#define SEQ    4096
#define NBATCH 4
#define DMODEL 1024

static __device__ __forceinline__ unsigned short f32_to_bf16(float f) {
  unsigned u = __builtin_bit_cast(unsigned, f);
  u = (u + 0x7FFFu + ((u >> 16) & 1u)) >> 16;  // round-nearest-even
  return (unsigned short)u;
}

// ---------------- kernel 1: weights f32 -> bf16, MFMA-fragment order --------
// wfrag[((nt*32 + ks)*64 + lane)*8 + j] = W_mat[(nt&3)*16 + (lane&15)]
//                                             [ks*32 + (lane>>4)*8 + j]
__global__ __launch_bounds__(256) void wcvt_kernel(
    const float* __restrict__ wq, const float* __restrict__ wk,
    const float* __restrict__ wv, unsigned short* __restrict__ wfrag) {
  const int fid = blockIdx.x * 256 + threadIdx.x;  // 0..24575
  const int nt = fid >> 11, ks = (fid >> 6) & 31, lane = fid & 63;
  const int l16 = lane & 15, lq = lane >> 4;
  const float* w = (nt < 4) ? wq : (nt < 8) ? wk : wv;
  const float* src = w + ((nt & 3) * 16 + l16) * DMODEL + ks * 32 + lq * 8;
  short8 v;
#pragma unroll
  for (int j = 0; j < 8; ++j) v[j] = (short)f32_to_bf16(src[j]);
  *reinterpret_cast<short8*>(wfrag + (long)fid * 8) = v;
}

// ---------------- kernel 2: QKV projection, coalesced-store epilogue --------
// K-loop identical to R11 (reg-dbuf weights, 64KB swizzled x LDS). NEW: the
// epilogue stages all 12KB of block output in LDS in final fragment order
// (sub-dword LDS writes are cheap), then flushes with 3 coalesced 16B global
// stores per thread — replacing 24 scattered 2-byte global stores per thread
// (the suspected ~30us write-amplification cost, invariant across R2-R11).
__global__ __launch_bounds__(256, 1) void qkv_proj_kernel(
    const float* __restrict__ x, const unsigned short* __restrict__ wfrag,
    const float* __restrict__ bq, const float* __restrict__ bk,
    const float* __restrict__ bv,
    unsigned short* __restrict__ Qf, unsigned short* __restrict__ Kf,
    unsigned short* __restrict__ Vf) {
  __shared__ __align__(16) unsigned short lds_x[32 * 1024];  // 64KB swizzled
  const int tid = threadIdx.x, lane = tid & 63, wave = tid >> 6;
  const int l16 = lane & 15, lq = lane >> 4;
  const long rowbase = (long)blockIdx.x * 32;
  unsigned char* lx = (unsigned char*)lds_x;

  // ---- stage x tile (32 rows x 1024 f32), coalesced per 8-thread group ----
  {
    const int srow = tid >> 3, scol = (tid & 7) * 16;  // float units
    const float* xrow = x + (rowbase + srow) * DMODEL + scol;
    const int swz = (srow & 7) << 4;
    unsigned char* lbase = lx + srow * 2048;
#pragma unroll
    for (int s = 0; s < 8; ++s) {
      const f32x4 f0 = *reinterpret_cast<const f32x4*>(xrow + s * 128);
      const f32x4 f1 = *reinterpret_cast<const f32x4*>(xrow + s * 128 + 4);
      const f32x4 f2 = *reinterpret_cast<const f32x4*>(xrow + s * 128 + 8);
      const f32x4 f3 = *reinterpret_cast<const f32x4*>(xrow + s * 128 + 12);
      short8 s0, s1;
#pragma unroll
      for (int j = 0; j < 4; ++j) {
        s0[j]     = (short)f32_to_bf16(f0[j]);
        s0[4 + j] = (short)f32_to_bf16(f1[j]);
        s1[j]     = (short)f32_to_bf16(f2[j]);
        s1[4 + j] = (short)f32_to_bf16(f3[j]);
      }
      const int bcol = scol * 2 + s * 256;
      *reinterpret_cast<short8*>(lbase + (bcol ^ swz)) = s0;
      *reinterpret_cast<short8*>(lbase + ((bcol + 16) ^ swz)) = s1;
    }
  }
  __syncthreads();

  // ---- K-loop: wave owns nt-trio `wave` for both 16-row subtiles ----------
  const unsigned short* wbase = wfrag + (long)(3 * wave) * 16384 + lane * 8;

  short8 bw[12];  // current chunk's weights: [i][kc] at j = i*4+kc
#pragma unroll
  for (int j = 0; j < 12; ++j)
    bw[j] = *reinterpret_cast<const short8*>(
        wbase + (long)(j >> 2) * 16384 + (j & 3) * 512);

  f32x4 acc[3][2];
#pragma unroll
  for (int i = 0; i < 3; ++i)
#pragma unroll
    for (int s = 0; s < 2; ++s) acc[i][s] = (f32x4){0.f, 0.f, 0.f, 0.f};

#pragma unroll
  for (int ck = 0; ck < 8; ++ck) {
    short8 bn[12];  // next chunk's weights, issued before this chunk's MFMAs
    if (ck < 7) {
#pragma unroll
      for (int j = 0; j < 12; ++j)
        bn[j] = *reinterpret_cast<const short8*>(
            wbase + (long)(j >> 2) * 16384 + ((ck + 1) * 4 + (j & 3)) * 512);
    }
    short8 a[4][2];
#pragma unroll
    for (int kc = 0; kc < 4; ++kc)
#pragma unroll
      for (int sub = 0; sub < 2; ++sub) {
        const int row = sub * 16 + l16;
        a[kc][sub] = *reinterpret_cast<const short8*>(
            lx + row * 2048 +
            (((ck * 4 + kc) * 64 + lq * 16) ^ ((row & 7) << 4)));
      }
#pragma unroll
    for (int kc = 0; kc < 4; ++kc)
#pragma unroll
      for (int i = 0; i < 3; ++i) {
        acc[i][0] = __builtin_amdgcn_mfma_f32_16x16x32_bf16(
            a[kc][0], bw[i * 4 + kc], acc[i][0], 0, 0, 0);
        acc[i][1] = __builtin_amdgcn_mfma_f32_16x16x32_bf16(
            a[kc][1], bw[i * 4 + kc], acc[i][1], 0, 0, 0);
      }
    if (ck < 7) {
#pragma unroll
      for (int j = 0; j < 12; ++j) bw[j] = bn[j];  // SSA rename (full unroll)
    }
  }

  // ---- epilogue v2: LDS-stage in fragment order, coalesced 16B flush ------
  __syncthreads();  // all waves done reading lds_x; reuse it as out-stage
  unsigned short* lo = lds_x;  // [0,2048): Qf  [2048,4096): Kf  [4096,6144): Vf

#pragma unroll
  for (int i = 0; i < 3; ++i) {
    const int nt = 3 * wave + i;
    const int mat = nt >> 2;
    const int dcol = ((nt & 3) << 4) | l16;
    const float bias = (mat == 0 ? bq : mat == 1 ? bk : bv)[dcol];
    const int c = dcol >> 5, lqp = (dcol >> 3) & 3, jj = dcol & 7;
#pragma unroll
    for (int sub = 0; sub < 2; ++sub)
#pragma unroll
      for (int rr = 0; rr < 4; ++rr) {
        const int tl = sub * 16 + lq * 4 + rr;  // local row 0..31
        const float sum = acc[i][sub][rr] + bias;
        if (mat == 0) {
          lo[(((tl >> 4) * 2 + c) * 64 + lqp * 16 + (tl & 15)) * 8 + jj] =
              f32_to_bf16(sum * 0.125f);  // fold 1/sqrt(64)
        } else if (mat == 1) {
          lo[2048 + (((tl >> 4) * 2 + c) * 64 + lqp * 16 + (tl & 15)) * 8 + jj] =
              f32_to_bf16(sum);
        } else {
          lo[4096 + (nt & 3) * 512 +
             (((tl >> 3) & 3) * 16 + (dcol & 15)) * 8 + (tl & 7)] =
              f32_to_bf16(sum);
        }
      }
  }
  __syncthreads();
  {
    // Qf/Kf block regions are contiguous 2048 shorts (t>>4 ≡ (t>>6)*4+((t>>4)&3));
    // Vf is 4 chunks of 512 shorts at stride 1024.
    const long qb = (rowbase >> 4) * 1024;
    const int g = tid >> 6;  // wave id = Vf chunk (dt)
    const long vb = (((rowbase >> 6) * 4 + g) * 2 + ((rowbase >> 5) & 1)) * 512;
    *reinterpret_cast<short8*>(Qf + qb + tid * 8) =
        *reinterpret_cast<const short8*>(lo + tid * 8);
    *reinterpret_cast<short8*>(Kf + qb + tid * 8) =
        *reinterpret_cast<const short8*>(lo + 2048 + tid * 8);
    *reinterpret_cast<short8*>(Vf + vb + (tid & 63) * 8) =
        *reinterpret_cast<const short8*>(lo + 4096 + tid * 8);
  }
}

// ---------------- kernel 3: causal flash attention, swapped-operand ---------
// Unchanged from R4 (proven): 4 waves split KV round-robin, lane-local softmax
// via swapped MFMA operands, fragment-ordered Qf/Kf/Vf loads.
__global__ __launch_bounds__(256) void attn_kernel(
    const unsigned short* __restrict__ Qf, const unsigned short* __restrict__ Kf,
    const unsigned short* __restrict__ Vf, float* __restrict__ out) {
  __shared__ __align__(16) unsigned short p_lds[4][16][72];  // [wave][q][k]
  __shared__ __align__(16) float lds_o[4][16][68];           // [wave][q][d]
  __shared__ float lds_ml[4][16][2];
  __shared__ float lds_gl[16];

  const int tid = threadIdx.x;
  const int lane = tid & 63;
  const int wave = tid >> 6;
  const int l16 = lane & 15, lq = lane >> 4;
  const int b = blockIdx.y;
  const int tile = 255 - blockIdx.x;  // heavy tiles dispatch first
  const int qbase = tile * 16;
  const long qrow = (long)b * SEQ + qbase;

  short8 qf[2];
#pragma unroll
  for (int c = 0; c < 2; ++c)
    qf[c] = *reinterpret_cast<const short8*>(
        Qf + ((qrow >> 4) * 2 + c) * 512 + lane * 8);

  f32x4 o[4];  // O^T: o[dt][r] = O[q=l16][d=dt*16+lq*4+r]
#pragma unroll
  for (int dt = 0; dt < 4; ++dt) o[dt] = (f32x4){0.f, 0.f, 0.f, 0.f};
  float m = -INFINITY, ell = 0.f;  // per-lane state for q = qbase + l16

  const long ktile0 = (long)b * 64;
  const int nkv = qbase / 64 + 1;  // KV tiles of 64 cols
  for (int kt = wave; kt < nkv; kt += 4) {
    const int kvbase = kt * 64;
    const unsigned short* kb = Kf + (ktile0 + kt) * 4096 + lane * 8;
    const unsigned short* vb = Vf + (ktile0 + kt) * 4096 + lane * 8;
    f32x4 s[4];  // S^T: s[ct][r] = S[q=l16][k=kvbase+ct*16+lq*4+r]
#pragma unroll
    for (int ct = 0; ct < 4; ++ct) s[ct] = (f32x4){0.f, 0.f, 0.f, 0.f};
#pragma unroll
    for (int ct = 0; ct < 4; ++ct)
#pragma unroll
      for (int c = 0; c < 2; ++c) {
        short8 kf = *reinterpret_cast<const short8*>(kb + (ct * 2 + c) * 512);
        s[ct] = __builtin_amdgcn_mfma_f32_16x16x32_bf16(kf, qf[c], s[ct], 0, 0, 0);
      }
    if (kt == nkv - 1) {  // only the diagonal tile needs masking
      const int qg = qbase + l16;
#pragma unroll
      for (int ct = 0; ct < 4; ++ct)
#pragma unroll
        for (int r = 0; r < 4; ++r)
          if (kvbase + ct * 16 + lq * 4 + r > qg) s[ct][r] = -INFINITY;
    }
    // lane-local softmax over 16 held k values + 4-lane-group reduce
    float mx = -INFINITY;
#pragma unroll
    for (int ct = 0; ct < 4; ++ct)
#pragma unroll
      for (int r = 0; r < 4; ++r) mx = fmaxf(mx, s[ct][r]);
    mx = fmaxf(mx, __shfl_xor(mx, 16, 64));
    mx = fmaxf(mx, __shfl_xor(mx, 32, 64));
    const float nm = fmaxf(m, mx);
    const float alpha = __expf(m - nm);  // exp(-inf)=0 on first tile
    float rs = 0.f;
#pragma unroll
    for (int ct = 0; ct < 4; ++ct)
#pragma unroll
      for (int r = 0; r < 4; ++r) {
        const float p = __expf(s[ct][r] - nm);
        s[ct][r] = p;
        rs += p;
      }
    rs += __shfl_xor(rs, 16, 64);
    rs += __shfl_xor(rs, 32, 64);
    ell = ell * alpha + rs;
    m = nm;
#pragma unroll
    for (int dt = 0; dt < 4; ++dt) o[dt] *= alpha;
    // P^T (regs) -> p_lds[q][k] -> B-frag for PV. Per-wave buffer, no barrier.
#pragma unroll
    for (int ct = 0; ct < 4; ++ct)
#pragma unroll
      for (int r = 0; r < 4; ++r)
        p_lds[wave][l16][ct * 16 + lq * 4 + r] = f32_to_bf16(s[ct][r]);
    short8 pf[2];
#pragma unroll
    for (int c = 0; c < 2; ++c)
      pf[c] = *reinterpret_cast<const short8*>(&p_lds[wave][l16][c * 32 + lq * 8]);
#pragma unroll
    for (int dt = 0; dt < 4; ++dt)
#pragma unroll
      for (int c = 0; c < 2; ++c) {
        short8 vf = *reinterpret_cast<const short8*>(vb + (dt * 2 + c) * 512);
        o[dt] = __builtin_amdgcn_mfma_f32_16x16x32_bf16(vf, pf[c], o[dt], 0, 0, 0);
      }
  }

  // ---- cross-wave combine ----
  if (lane < 16) {
    lds_ml[wave][l16][0] = m;
    lds_ml[wave][l16][1] = ell;
  }
  __syncthreads();
  const float m0 = lds_ml[0][l16][0], m1 = lds_ml[1][l16][0];
  const float m2 = lds_ml[2][l16][0], m3 = lds_ml[3][l16][0];
  const float g = fmaxf(fmaxf(m0, m1), fmaxf(m2, m3));
  const float gl = lds_ml[0][l16][1] * __expf(m0 - g) +
                   lds_ml[1][l16][1] * __expf(m1 - g) +
                   lds_ml[2][l16][1] * __expf(m2 - g) +
                   lds_ml[3][l16][1] * __expf(m3 - g);
  const float myscale = __expf(m - g);
  if (wave == 0 && lane < 16) lds_gl[l16] = gl;
#pragma unroll
  for (int dt = 0; dt < 4; ++dt)
#pragma unroll
    for (int r = 0; r < 4; ++r)
      lds_o[wave][l16][dt * 16 + lq * 4 + r] = o[dt][r] * myscale;
  __syncthreads();
#pragma unroll
  for (int j = 0; j < 4; ++j) {
    const int e = tid + 256 * j;
    const int row = e >> 6, col = e & 63;
    const float sum = lds_o[0][row][col] + lds_o[1][row][col] +
                      lds_o[2][row][col] + lds_o[3][row][col];
    out[(qrow + row) * D_KV + col] = sum / lds_gl[row];
  }
}

// ---------------- launch ----------------------------------------------------
extern "C" void kernel_launch(void* const* d_in, const int* in_sizes, int n_in,
                              void* d_out, int out_size, void* d_ws, size_t ws_size,
                              hipStream_t stream) {
  const float* x  = (const float*)d_in[0];
  const float* wq = (const float*)d_in[1];
  const float* bq = (const float*)d_in[2];
  const float* wk = (const float*)d_in[3];
  const float* bk = (const float*)d_in[4];
  const float* wv = (const float*)d_in[5];
  const float* bv = (const float*)d_in[6];
  float* out = (float*)d_out;

  unsigned short* ws    = (unsigned short*)d_ws;
  unsigned short* wfrag = ws;              // 12*32*64*8 = 196608 shorts (384KB)
  unsigned short* Qf    = ws + 196608;     // 1024 tiles * 1024 = 1048576
  unsigned short* Kf    = Qf + 1048576;    // 256 kv-tiles * 4096
  unsigned short* Vf    = Kf + 1048576;

  wcvt_kernel<<<96, 256, 0, stream>>>(wq, wk, wv, wfrag);
  qkv_proj_kernel<<<512, 256, 0, stream>>>(x, wfrag, bq, bk, bv, Qf, Kf, Vf);
  dim3 ag(256, NBATCH);
  attn_kernel<<<ag, 256, 0, stream>>>(Qf, Kf, Vf, out);
}